// Round 6
// baseline (223.287 us; speedup 1.0000x reference)
//
#include <hip/hip_runtime.h>
#include <hip/hip_bf16.h>

// TelephoneAttentionBlock: x[4,4096,1024] fp32 -> RMSNorm -> QKV (bf16 MFMA GEMM)
// -> windowed block attention (16 heads, dh=64, window 128) -> Wo GEMM + residual -> fp32 out.
// Round 6: GEMM rebuilt as BK=32 triple-buffered ring, ONE barrier per K-tile
// (was 16), counted vmcnt(4), free wave drift for LDS/MFMA overlap.

typedef __attribute__((ext_vector_type(8))) short s8v;   // 8 bf16 (4 VGPRs)
typedef __attribute__((ext_vector_type(4))) float f4v;   // MFMA accumulator

#define MFMA_BF16(A, B, C) __builtin_amdgcn_mfma_f32_16x16x32_bf16((A), (B), (C), 0, 0, 0)

static __device__ __forceinline__ void gload_lds16(const void* g, void* l) {
    // async global->LDS, 16B per lane; LDS dest = wave-uniform base + lane*16
    __builtin_amdgcn_global_load_lds((const __attribute__((address_space(1))) void*)g,
                                     (__attribute__((address_space(3))) void*)l, 16, 0, 0);
}

static __device__ __forceinline__ unsigned short f2bf(float f) {
    return __builtin_bit_cast(unsigned short, __float2bfloat16(f));
}

// ---------------- weight cast + transpose: in[K][N] fp32 -> out[N][K] bf16 ----------------
__global__ __launch_bounds__(256) void transpose_cast_kernel(const float* __restrict__ in,
                                                             unsigned short* __restrict__ out,
                                                             int K, int N) {
    __shared__ float tile[32][33];
    int nbk = K >> 5;
    int bk = blockIdx.x % nbk;
    int bn = blockIdx.x / nbk;
    int tx = threadIdx.x & 31, ty = threadIdx.x >> 5;
#pragma unroll
    for (int i = 0; i < 4; i++) {
        int r = ty + i * 8;
        tile[r][tx] = in[(size_t)(bk * 32 + r) * N + bn * 32 + tx];
    }
    __syncthreads();
#pragma unroll
    for (int i = 0; i < 4; i++) {
        int r = ty + i * 8;
        out[(size_t)(bn * 32 + r) * K + bk * 32 + tx] = f2bf(tile[tx][r]);
    }
}

// ---------------- RMSNorm: x fp32 [M][1024] -> xn bf16 ----------------
__global__ __launch_bounds__(256) void rmsnorm_kernel(const float* __restrict__ x,
                                                      const float* __restrict__ g,
                                                      unsigned short* __restrict__ xn) {
    const int D = 1024;
    int row = blockIdx.x;
    int t = threadIdx.x;
    float4 v = ((const float4*)(x + (size_t)row * D))[t];
    float ss = v.x * v.x + v.y * v.y + v.z * v.z + v.w * v.w;
#pragma unroll
    for (int off = 32; off >= 1; off >>= 1) ss += __shfl_xor(ss, off, 64);
    __shared__ float partials[4];
    if ((t & 63) == 0) partials[t >> 6] = ss;
    __syncthreads();
    float tot = partials[0] + partials[1] + partials[2] + partials[3];
    float scale = rsqrtf(tot * (1.0f / D) + 1e-6f);
    float4 gv = ((const float4*)g)[t];
    ushort4 o;
    o.x = f2bf(v.x * scale * gv.x);
    o.y = f2bf(v.y * scale * gv.y);
    o.z = f2bf(v.z * scale * gv.z);
    o.w = f2bf(v.w * scale * gv.w);
    ((ushort4*)xn)[(size_t)row * (D / 4) + t] = o;
}

// ---------------- GEMM 256x256, BK=32, triple-buffer ring, 1 barrier/K-tile ----------------
// C[M][N] = A[M][K] * Bt[N][K]^T. MODE 0: C -> bf16. MODE 1: C -> fp32 = resid + acc.
// 512 threads = 8 waves (2M x 4N), per-wave 128x64 output (acc 8x4 f4v).
// LDS 96KB = 3 bufs x 32KB; buf r: A [0,16K) 256 rows x 64B, B [16K,32K).
// Swizzle (64B rows, 4 x 16B slots): stored slot s holds global k-slot s ^ ((row>>1)&3);
// DMA write lane l -> row l>>2, slot l&3, global slot (l&3)^((l>>3)&3) (pre-swizzled src);
// read slot = hl ^ ((ll>>1)&3)  => 1KB byte-distinct per wave-read (conflict-minimal).
// Ring: during tile t stage t+2; end-of-tile lgkmcnt(0) (WAR) + vmcnt(4) (t+1 arrived,
// t+2 in flight) + s_barrier. Never vmcnt(0) in steady state.
template <int MODE>
__global__ __launch_bounds__(512, 2) void gemm256_kernel(const unsigned short* __restrict__ A,
                                                         const unsigned short* __restrict__ Bt,
                                                         unsigned short* __restrict__ Cb,
                                                         float* __restrict__ Cf,
                                                         const float* __restrict__ resid,
                                                         int M, int N, int K) {
    __shared__ __align__(16) char lds_s[98304];

    const int nbn = N >> 8;
    const int nwg = (M >> 8) * nbn;
    int bid = blockIdx.x;
    int cpx = nwg >> 3;                        // grids are multiples of 8
    int wg = (bid & 7) * cpx + (bid >> 3);     // XCD-aware swizzle (bijective)
    int bm = wg / nbn, bn = wg % nbn;

    int tid = threadIdx.x, lane = tid & 63, w = tid >> 6;
    int wm = w >> 2, wn = w & 3;               // wave tile: rows wm*128, cols wn*64
    int hl = lane >> 4, ll = lane & 15;

    const unsigned short* Ab = A + (size_t)bm * 256 * K;
    const unsigned short* Bb = Bt + (size_t)bn * 256 * K;

    // staging: wave w covers rows [w*32, w*32+32) of A and B, 2 insts each (16 rows/inst)
    int lrow = lane >> 2;                                // row within 16-row chunk
    int sslot = ((lane & 3) ^ ((lane >> 3) & 3)) * 8;    // pre-swizzled src k-elem offset
    const unsigned short* gAw = Ab + (size_t)(w * 32 + lrow) * K + sslot;
    const unsigned short* gBw = Bb + (size_t)(w * 32 + lrow) * K + sslot;
    char* ldst = lds_s + w * 2048;

    // read-side bases (row*64B + swizzled slot)
    int rslot = (hl ^ ((ll >> 1) & 3)) * 16;
    const char* ldsA = lds_s + (wm * 128 + ll) * 64 + rslot;
    const char* ldsB = lds_s + 16384 + (wn * 64 + ll) * 64 + rslot;

    const int NT = K >> 5;                     // 32 K-tiles for K=1024

    f4v acc[8][4] = {};

#define STAGE(t_) do {                                                                    \
        char* l_ = ldst + ((t_) % 3) * 32768;                                             \
        gload_lds16(gAw + (t_) * 32, l_);                                                 \
        gload_lds16(gAw + (t_) * 32 + 16 * K, l_ + 1024);                                 \
        gload_lds16(gBw + (t_) * 32, l_ + 16384);                                         \
        gload_lds16(gBw + (t_) * 32 + 16 * K, l_ + 16384 + 1024);                         \
    } while (0)

    // prologue: tiles 0 and 1 in flight; wait tile 0 (4 oldest), barrier
    STAGE(0);
    STAGE(1);
    asm volatile("s_waitcnt vmcnt(4)" ::: "memory");
    asm volatile("s_barrier" ::: "memory");

    for (int t = 0; t < NT; t++) {
        int bufo = (t % 3) * 32768;
        if (t + 2 < NT) STAGE(t + 2);          // into buf[(t+2)%3]; safe: its readers
                                               // (tile t-1) drained at last barrier
        const char* bufA = ldsA + bufo;
        const char* bufB = ldsB + bufo;
        s8v bf[4];
#pragma unroll
        for (int n = 0; n < 4; n++) bf[n] = *(const s8v*)(bufB + n * 1024);
        __builtin_amdgcn_s_setprio(1);
#pragma unroll
        for (int m = 0; m < 8; m++) {
            s8v am = *(const s8v*)(bufA + m * 1024);
#pragma unroll
            for (int n = 0; n < 4; n++) acc[m][n] = MFMA_BF16(am, bf[n], acc[m][n]);
        }
        __builtin_amdgcn_s_setprio(0);
        if (t + 1 < NT) {
            // lgkmcnt(0): my ds_reads of buf[t%3] complete (WAR vs next stage);
            // vmcnt: t+1's 4 loads arrived (t+2's 4 may stay in flight)
            if (t + 2 < NT)
                asm volatile("s_waitcnt vmcnt(4) lgkmcnt(0)" ::: "memory");
            else
                asm volatile("s_waitcnt vmcnt(0) lgkmcnt(0)" ::: "memory");
            asm volatile("s_barrier" ::: "memory");
        }
    }
#undef STAGE

    // epilogue: C write
    int crow0 = bm * 256 + wm * 128;
    int ccol0 = bn * 256 + wn * 64;
#pragma unroll
    for (int m = 0; m < 8; m++) {
#pragma unroll
        for (int r = 0; r < 4; r++) {
            int row = crow0 + m * 16 + hl * 4 + r;
#pragma unroll
            for (int n = 0; n < 4; n++) {
                int col = ccol0 + n * 16 + ll;
                float val = acc[m][n][r];
                if (MODE == 0) {
                    Cb[(size_t)row * N + col] = f2bf(val);
                } else {
                    size_t idx = (size_t)row * N + col;
                    Cf[idx] = resid[idx] + val;
                }
            }
        }
    }
}

// ---------------- windowed block attention (band-limited) ----------------
// grid: B*H*NB blocks; 256 threads = 4 waves x 32 query rows.
// Per m-frag (16 queries at frag index m0 = 2w+mf), only key frags m0..m0+8 are unmasked.
// LDS: [0,32768) K [256 keys][64 dh] XOR-swizzled (reused as Vt [64][264] swizzled after QK^T);
//      [33792, 44032) per-wave P staging [32][40].
__global__ __launch_bounds__(256, 3) void attn_kernel(const unsigned short* __restrict__ qkv,
                                                      unsigned short* __restrict__ obuf) {
    constexpr int S = 4096, D = 1024, H = 16, W = 128, NB = 32;
    constexpr int TD = 3 * D;
    constexpr int PS = 40;

    __shared__ __align__(16) char smem[44032];
    unsigned short* KV = (unsigned short*)smem;

    int bid = blockIdx.x;
    int blk = bid % NB;
    int h = (bid / NB) % H;
    int b = bid / (NB * H);

    int tid = threadIdx.x, lane = tid & 63, w = tid >> 6;
    int hl = lane >> 4, ll = lane & 15;
    unsigned short* Ps = (unsigned short*)(smem + 33792) + w * 32 * PS;

    int kbase = blk * W - W;            // global s of extended key 0
    size_t rowbase = (size_t)(b * S);

    // ---- stage K [256][64] via async global_load_lds, source pre-swizzled ----
    {
        int lr = lane >> 3;                       // row within 8-row chunk
        int scb = ((lane & 7) ^ lr) * 16;         // swizzled source byte col
#pragma unroll
        for (int r = 0; r < 8; r++) {
            int row = r * 32 + w * 8 + lr;        // ext key index
            int s = kbase + row;
            s = s < 0 ? 0 : s;                    // clamp (blk 0: masked later, finite data)
            const char* src = (const char*)(qkv + (rowbase + s) * TD + D + h * 64) + scb;
            char* dst = smem + (size_t)(r * 32 + w * 8) * 128 + lane * 16;
            gload_lds16(src, dst);
        }
    }

    // ---- Q fragments ----
    s8v qf[2][2];
    {
        const unsigned short* qb = qkv + (rowbase + blk * W + w * 32) * TD + h * 64;
#pragma unroll
        for (int mf = 0; mf < 2; mf++)
#pragma unroll
            for (int ks = 0; ks < 2; ks++)
                qf[mf][ks] = *(const s8v*)(qb + (size_t)(mf * 16 + ll) * TD + ks * 32 + hl * 8);
    }

    // ---- prefetch V into regs: lane owns 8x8 block V[k0..k0+7][d0..d0+7] ----
    s8v vreg[8];
    {
        int k0 = w * 64 + (lane >> 3) * 8;
        int d0 = (lane & 7) * 8;
#pragma unroll
        for (int it = 0; it < 8; it++) {
            int s = kbase + k0 + it;
            s = s < 0 ? 0 : s;
            vreg[it] = *(const s8v*)(qkv + (rowbase + s) * TD + 2 * D + h * 64 + d0);
        }
    }
    __syncthreads();   // K in LDS (V regs also arrived)

    // ---- QK^T: band of 9 key frags per m-frag; kf shared across mf via 10-frag sweep ----
    f4v sc[2][9] = {};
    int g0 = w * 2;
    __builtin_amdgcn_s_setprio(1);
#pragma unroll
    for (int gi = 0; gi < 10; gi++) {
#pragma unroll
        for (int ks = 0; ks < 2; ks++) {
            int row = (g0 + gi) * 16 + ll;
            s8v kf = *(const s8v*)(smem + (size_t)row * 128 +
                                   (((unsigned)(ks * 64 + hl * 16)) ^ ((ll & 7) << 4)));
            if (gi < 9) sc[0][gi] = MFMA_BF16(qf[0][ks], kf, sc[0][gi]);
            if (gi > 0) sc[1][gi - 1] = MFMA_BF16(qf[1][ks], kf, sc[1][gi - 1]);
        }
    }
    __builtin_amdgcn_s_setprio(0);

    // ---- mask + scale + softmax (rows across 16 lanes of quarter-wave) ----
    float linv[2][4];
#pragma unroll
    for (int mf = 0; mf < 2; mf++) {
#pragma unroll
        for (int r = 0; r < 4; r++) {
            int ip = hl * 4 + r;                  // query pos within m-frag
            float mx = -1e30f;
#pragma unroll
            for (int nf = 0; nf < 9; nf++) {
                bool ok = (nf > 0 || ll > ip) && (nf < 8 || ll <= ip) &&
                          (blk > 0 || (g0 + mf + nf) >= 8);
                float sval = ok ? sc[mf][nf][r] * 0.125f : -1e30f;
                sc[mf][nf][r] = sval;
                mx = fmaxf(mx, sval);
            }
#pragma unroll
            for (int off = 1; off < 16; off <<= 1) mx = fmaxf(mx, __shfl_xor(mx, off, 64));
            float sum = 0.f;
#pragma unroll
            for (int nf = 0; nf < 9; nf++) {
                float p = __expf(sc[mf][nf][r] - mx);
                sc[mf][nf][r] = p;
                sum += p;
            }
#pragma unroll
            for (int off = 1; off < 16; off <<= 1) sum += __shfl_xor(sum, off, 64);
            linv[mf][r] = 1.f / sum;
        }
    }

    __syncthreads();   // all waves done reading K

    // ---- write V transposed: in-register 8x8 transpose, 8 x ds_write_b128 ----
    // Vt[d][k'] with k' = k ^ (((d>>3)&7)<<3); read side applies the same XOR.
    {
        int k0 = w * 64 + (lane >> 3) * 8;
        int d0 = (lane & 7) * 8;
#pragma unroll
        for (int e = 0; e < 8; e++) {
            int d = d0 + e;
            s8v tmp;
#pragma unroll
            for (int i = 0; i < 8; i++) tmp[i] = vreg[i][e];
            *(s8v*)(KV + d * 264 + (k0 ^ (((d >> 3) & 7) << 3))) = tmp;
        }
    }
    __syncthreads();   // Vt visible

    // ---- PV: 5 chunks of 32 keys starting at wave base w*32 ----
    f4v o[2][4] = {};
#pragma unroll
    for (int c = 0; c < 5; c++) {
#pragma unroll
        for (int mf = 0; mf < 2; mf++) {
#pragma unroll
            for (int j16 = 0; j16 < 2; j16++) {
                int nf = c * 2 + j16 - mf;
                int nfc = nf < 0 ? 0 : (nf > 8 ? 8 : nf);
#pragma unroll
                for (int r = 0; r < 4; r++) {
                    float val = (nf >= 0 && nf < 9) ? sc[mf][nfc][r] : 0.f;
                    Ps[(mf * 16 + hl * 4 + r) * PS + j16 * 16 + ll] = f2bf(val);
                }
            }
        }
        asm volatile("s_waitcnt lgkmcnt(0)" ::: "memory");
        s8v pa[2];
        pa[0] = *(const s8v*)(Ps + ll * PS + hl * 8);
        pa[1] = *(const s8v*)(Ps + (16 + ll) * PS + hl * 8);
        int cb = (w + c) * 32;
        __builtin_amdgcn_s_setprio(1);
#pragma unroll
        for (int nd = 0; nd < 4; nd++) {
            int d = nd * 16 + ll;
            int kk = (cb + hl * 8) ^ (((d >> 3) & 7) << 3);
            s8v vb = *(const s8v*)(KV + d * 264 + kk);
            o[0][nd] = MFMA_BF16(pa[0], vb, o[0][nd]);
            o[1][nd] = MFMA_BF16(pa[1], vb, o[1][nd]);
        }
        __builtin_amdgcn_s_setprio(0);
    }

    // ---- write O (bf16) ----
    unsigned short* ob = obuf + (rowbase + blk * W + w * 32) * D + h * 64;
#pragma unroll
    for (int mf = 0; mf < 2; mf++)
#pragma unroll
        for (int r = 0; r < 4; r++) {
            int row = mf * 16 + hl * 4 + r;
#pragma unroll
            for (int nd = 0; nd < 4; nd++)
                ob[(size_t)row * D + nd * 16 + ll] = f2bf(o[mf][nd][r] * linv[mf][r]);
        }
}

// ---------------- launch ----------------
extern "C" void kernel_launch(void* const* d_in, const int* in_sizes, int n_in,
                              void* d_out, int out_size, void* d_ws, size_t ws_size,
                              hipStream_t stream) {
    const float* x = (const float*)d_in[0];
    const float* g = (const float*)d_in[1];
    const float* Wqkv = (const float*)d_in[2];
    const float* Wo = (const float*)d_in[3];
    float* out = (float*)d_out;

    const int S = 4096, D = 1024, B = 4;
    const int M = B * S;  // 16384
    const int N3 = 3 * D; // 3072

    // workspace layout (bytes):
    //   [0, 6291456)            WqkvT bf16 [3072][1024]
    //   [6291456, 8388608)      WoT   bf16 [1024][1024]
    //   [8388608, 41943040)     xn    bf16 [16384][1024]  (reused as attention output)
    //   [41943040, 142606336)   qkv   bf16 [16384][3072]
    char* ws = (char*)d_ws;
    unsigned short* WqkvT = (unsigned short*)ws;
    unsigned short* WoT = (unsigned short*)(ws + 6291456);
    unsigned short* xn = (unsigned short*)(ws + 8388608);
    unsigned short* qkv = (unsigned short*)(ws + 41943040);

    transpose_cast_kernel<<<dim3((D / 32) * (N3 / 32)), dim3(256), 0, stream>>>(Wqkv, WqkvT, D, N3);
    transpose_cast_kernel<<<dim3((D / 32) * (D / 32)), dim3(256), 0, stream>>>(Wo, WoT, D, D);
    rmsnorm_kernel<<<dim3(M), dim3(256), 0, stream>>>(x, g, xn);
    gemm256_kernel<0><<<dim3((M / 256) * (N3 / 256)), dim3(512), 0, stream>>>(
        xn, WqkvT, qkv, nullptr, nullptr, M, N3, D);
    attn_kernel<<<dim3(B * 16 * (S / 128)), dim3(256), 0, stream>>>(qkv, xn);
    gemm256_kernel<1><<<dim3((M / 256) * (D / 256)), dim3(512), 0, stream>>>(
        xn, WoT, nullptr, out, x, M, D, D);
}

// Round 7
// 217.710 us; speedup vs baseline: 1.0256x; 1.0256x over previous
//
#include <hip/hip_runtime.h>
#include <hip/hip_bf16.h>

// TelephoneAttentionBlock: x[4,4096,1024] fp32 -> RMSNorm -> QKV (bf16 MFMA GEMM)
// -> windowed block attention (16 heads, dh=64, window 128) -> Wo GEMM + residual -> fp32 out.
// Round 7: GEMM = BK=32, 4-buffer LDS ring + REGISTER fragment double-buffering:
// tile t's MFMA burst runs on resident regs while tile t+1's ds_reads are in flight
// (A into alternate named set; B refreshed in-burst after last use). Counted vmcnt(4).

typedef __attribute__((ext_vector_type(8))) short s8v;   // 8 bf16 (4 VGPRs)
typedef __attribute__((ext_vector_type(4))) float f4v;   // MFMA accumulator

#define MFMA_BF16(A, B, C) __builtin_amdgcn_mfma_f32_16x16x32_bf16((A), (B), (C), 0, 0, 0)

static __device__ __forceinline__ void gload_lds16(const void* g, void* l) {
    // async global->LDS, 16B per lane; LDS dest = wave-uniform base + lane*16
    __builtin_amdgcn_global_load_lds((const __attribute__((address_space(1))) void*)g,
                                     (__attribute__((address_space(3))) void*)l, 16, 0, 0);
}

static __device__ __forceinline__ unsigned short f2bf(float f) {
    return __builtin_bit_cast(unsigned short, __float2bfloat16(f));
}

// ---------------- weight cast + transpose: in[K][N] fp32 -> out[N][K] bf16 ----------------
__global__ __launch_bounds__(256) void transpose_cast_kernel(const float* __restrict__ in,
                                                             unsigned short* __restrict__ out,
                                                             int K, int N) {
    __shared__ float tile[32][33];
    int nbk = K >> 5;
    int bk = blockIdx.x % nbk;
    int bn = blockIdx.x / nbk;
    int tx = threadIdx.x & 31, ty = threadIdx.x >> 5;
#pragma unroll
    for (int i = 0; i < 4; i++) {
        int r = ty + i * 8;
        tile[r][tx] = in[(size_t)(bk * 32 + r) * N + bn * 32 + tx];
    }
    __syncthreads();
#pragma unroll
    for (int i = 0; i < 4; i++) {
        int r = ty + i * 8;
        out[(size_t)(bn * 32 + r) * K + bk * 32 + tx] = f2bf(tile[tx][r]);
    }
}

// ---------------- RMSNorm: x fp32 [M][1024] -> xn bf16 ----------------
__global__ __launch_bounds__(256) void rmsnorm_kernel(const float* __restrict__ x,
                                                      const float* __restrict__ g,
                                                      unsigned short* __restrict__ xn) {
    const int D = 1024;
    int row = blockIdx.x;
    int t = threadIdx.x;
    float4 v = ((const float4*)(x + (size_t)row * D))[t];
    float ss = v.x * v.x + v.y * v.y + v.z * v.z + v.w * v.w;
#pragma unroll
    for (int off = 32; off >= 1; off >>= 1) ss += __shfl_xor(ss, off, 64);
    __shared__ float partials[4];
    if ((t & 63) == 0) partials[t >> 6] = ss;
    __syncthreads();
    float tot = partials[0] + partials[1] + partials[2] + partials[3];
    float scale = rsqrtf(tot * (1.0f / D) + 1e-6f);
    float4 gv = ((const float4*)g)[t];
    ushort4 o;
    o.x = f2bf(v.x * scale * gv.x);
    o.y = f2bf(v.y * scale * gv.y);
    o.z = f2bf(v.z * scale * gv.z);
    o.w = f2bf(v.w * scale * gv.w);
    ((ushort4*)xn)[(size_t)row * (D / 4) + t] = o;
}

// ---------------- GEMM 256x256, BK=32, 4-buf ring + register frag double-buffer ----------------
// C[M][N] = A[M][K] * Bt[N][K]^T. MODE 0: C -> bf16. MODE 1: C -> fp32 = resid + acc.
// 512 threads = 8 waves (2M x 4N), per-wave 128x64 output (acc 8x4 f4v = 128 regs).
// LDS 128KB = 4 bufs x 32KB; buf: A [0,16K) 256 rows x 64B, B [16K,32K).
// Swizzle (64B rows, 4 x 16B slots): LDS[r][s] = global[r][s ^ ((r>>1)&3)];
// store via pre-swizzled global src (lane l: row l>>2, src slot (l&3)^((l>>3)&3));
// read slot = hl ^ ((ll>>1)&3). Verified conflict-free in R6 (SQ_LDS_BANK_CONFLICT = 0).
// Pipeline invariant entering tile t: frags[t] in regs; buf[(t+1)&3] complete;
// in flight: t+2's 4 loads (+t+3's after STAGE). End of t: vmcnt(4) -> t+2 done.
template <int MODE>
__global__ __launch_bounds__(512, 2) void gemm256_kernel(const unsigned short* __restrict__ A,
                                                         const unsigned short* __restrict__ Bt,
                                                         unsigned short* __restrict__ Cb,
                                                         float* __restrict__ Cf,
                                                         const float* __restrict__ resid,
                                                         int M, int N, int K) {
    __shared__ __align__(16) char lds_s[131072];

    const int nbn = N >> 8;
    const int nwg = (M >> 8) * nbn;
    int bid = blockIdx.x;
    int cpx = nwg >> 3;                        // grids are multiples of 8
    int wg = (bid & 7) * cpx + (bid >> 3);     // XCD-aware swizzle (bijective)
    int bm = wg / nbn, bn = wg % nbn;

    int tid = threadIdx.x, lane = tid & 63, w = tid >> 6;
    int wm = w >> 2, wn = w & 3;               // wave tile: rows wm*128, cols wn*64
    int hl = lane >> 4, ll = lane & 15;

    const unsigned short* Ab = A + (size_t)bm * 256 * K;
    const unsigned short* Bb = Bt + (size_t)bn * 256 * K;

    // staging: wave w covers rows [w*32, w*32+32) of A and B; 4 gloads per tile
    int lrow = lane >> 2;                                // row within 16-row chunk
    int sslot = ((lane & 3) ^ ((lane >> 3) & 3)) * 8;    // pre-swizzled src k-elem offset
    const unsigned short* gAw = Ab + (size_t)(w * 32 + lrow) * K + sslot;
    const unsigned short* gBw = Bb + (size_t)(w * 32 + lrow) * K + sslot;

    // read-side offsets (within a 32KB buffer)
    int rslot = (hl ^ ((ll >> 1) & 3)) * 16;
    const int ldsAoff = (wm * 128 + ll) * 64 + rslot;
    const int ldsBoff = 16384 + (wn * 64 + ll) * 64 + rslot;

    const int NT = K >> 5;                     // 32 K-tiles for K=1024

    f4v acc[8][4] = {};
    s8v aX[8], aY[8], bfr[4];

#define STAGE(t_) do {                                                                    \
        char* l_ = lds_s + ((t_) & 3) * 32768 + w * 2048;                                 \
        gload_lds16(gAw + (size_t)(t_) * 32, l_);                                         \
        gload_lds16(gAw + (size_t)(t_) * 32 + 16 * K, l_ + 1024);                         \
        gload_lds16(gBw + (size_t)(t_) * 32, l_ + 16384);                                 \
        gload_lds16(gBw + (size_t)(t_) * 32 + 16 * K, l_ + 16384 + 1024);                 \
    } while (0)

// one K-tile: CUR regs feed 32 MFMA; NXT regs filled from buf[(t+1)&3] meanwhile;
// B frags refreshed in-burst right after each one's last use this tile.
#define TILE(CUR, NXT, t_) do {                                                           \
        const char* nb_ = lds_s + (((t_) + 1) & 3) * 32768;                               \
        if ((t_) + 1 < NT) {                                                              \
            _Pragma("unroll") for (int m = 0; m < 8; m++)                                 \
                NXT[m] = *(const s8v*)(nb_ + ldsAoff + m * 1024);                         \
        }                                                                                 \
        if ((t_) + 3 < NT) STAGE((t_) + 3);                                               \
        __builtin_amdgcn_s_setprio(1);                                                    \
        _Pragma("unroll") for (int n = 0; n < 4; n++) {                                   \
            _Pragma("unroll") for (int m = 0; m < 8; m++)                                 \
                acc[m][n] = MFMA_BF16(CUR[m], bfr[n], acc[m][n]);                         \
            if ((t_) + 1 < NT)                                                            \
                bfr[n] = *(const s8v*)(nb_ + ldsBoff + n * 1024);                         \
        }                                                                                 \
        __builtin_amdgcn_s_setprio(0);                                                    \
        if ((t_) + 1 < NT) {                                                              \
            if ((t_) + 3 < NT) asm volatile("s_waitcnt vmcnt(4)" ::: "memory");           \
            else asm volatile("s_waitcnt vmcnt(0)" ::: "memory");                         \
            asm volatile("s_barrier" ::: "memory");                                       \
            __builtin_amdgcn_sched_barrier(0);                                            \
        }                                                                                 \
    } while (0)

    // prologue: stage tiles 0,1,2 (12 loads); wait bufs 0,1; load frags[0]
    STAGE(0);
    STAGE(1);
    STAGE(2);
    asm volatile("s_waitcnt vmcnt(4)" ::: "memory");   // bufs 0,1 complete; buf2 in flight
    asm volatile("s_barrier" ::: "memory");
    __builtin_amdgcn_sched_barrier(0);
    {
        const char* b0 = lds_s;
#pragma unroll
        for (int m = 0; m < 8; m++) aX[m] = *(const s8v*)(b0 + ldsAoff + m * 1024);
#pragma unroll
        for (int n = 0; n < 4; n++) bfr[n] = *(const s8v*)(b0 + ldsBoff + n * 1024);
    }

    for (int t = 0; t + 1 < NT; t += 2) {
        TILE(aX, aY, t);
        TILE(aY, aX, t + 1);
    }
#undef TILE
#undef STAGE

    // epilogue: C write
    int crow0 = bm * 256 + wm * 128;
    int ccol0 = bn * 256 + wn * 64;
#pragma unroll
    for (int m = 0; m < 8; m++) {
#pragma unroll
        for (int r = 0; r < 4; r++) {
            int row = crow0 + m * 16 + hl * 4 + r;
#pragma unroll
            for (int n = 0; n < 4; n++) {
                int col = ccol0 + n * 16 + ll;
                float val = acc[m][n][r];
                if (MODE == 0) {
                    Cb[(size_t)row * N + col] = f2bf(val);
                } else {
                    size_t idx = (size_t)row * N + col;
                    Cf[idx] = resid[idx] + val;
                }
            }
        }
    }
}

// ---------------- windowed block attention (band-limited) ----------------
// grid: B*H*NB blocks; 256 threads = 4 waves x 32 query rows.
// Per m-frag (16 queries at frag index m0 = 2w+mf), only key frags m0..m0+8 are unmasked.
// LDS: [0,32768) K [256 keys][64 dh] XOR-swizzled (reused as Vt [64][264] swizzled after QK^T);
//      [33792, 44032) per-wave P staging [32][40].
__global__ __launch_bounds__(256, 3) void attn_kernel(const unsigned short* __restrict__ qkv,
                                                      unsigned short* __restrict__ obuf) {
    constexpr int S = 4096, D = 1024, H = 16, W = 128, NB = 32;
    constexpr int TD = 3 * D;
    constexpr int PS = 40;

    __shared__ __align__(16) char smem[44032];
    unsigned short* KV = (unsigned short*)smem;

    int bid = blockIdx.x;
    int blk = bid % NB;
    int h = (bid / NB) % H;
    int b = bid / (NB * H);

    int tid = threadIdx.x, lane = tid & 63, w = tid >> 6;
    int hl = lane >> 4, ll = lane & 15;
    unsigned short* Ps = (unsigned short*)(smem + 33792) + w * 32 * PS;

    int kbase = blk * W - W;            // global s of extended key 0
    size_t rowbase = (size_t)(b * S);

    // ---- stage K [256][64] via async global_load_lds, source pre-swizzled ----
    {
        int lr = lane >> 3;                       // row within 8-row chunk
        int scb = ((lane & 7) ^ lr) * 16;         // swizzled source byte col
#pragma unroll
        for (int r = 0; r < 8; r++) {
            int row = r * 32 + w * 8 + lr;        // ext key index
            int s = kbase + row;
            s = s < 0 ? 0 : s;                    // clamp (blk 0: masked later, finite data)
            const char* src = (const char*)(qkv + (rowbase + s) * TD + D + h * 64) + scb;
            char* dst = smem + (size_t)(r * 32 + w * 8) * 128 + lane * 16;
            gload_lds16(src, dst);
        }
    }

    // ---- Q fragments ----
    s8v qf[2][2];
    {
        const unsigned short* qb = qkv + (rowbase + blk * W + w * 32) * TD + h * 64;
#pragma unroll
        for (int mf = 0; mf < 2; mf++)
#pragma unroll
            for (int ks = 0; ks < 2; ks++)
                qf[mf][ks] = *(const s8v*)(qb + (size_t)(mf * 16 + ll) * TD + ks * 32 + hl * 8);
    }

    // ---- prefetch V into regs: lane owns 8x8 block V[k0..k0+7][d0..d0+7] ----
    s8v vreg[8];
    {
        int k0 = w * 64 + (lane >> 3) * 8;
        int d0 = (lane & 7) * 8;
#pragma unroll
        for (int it = 0; it < 8; it++) {
            int s = kbase + k0 + it;
            s = s < 0 ? 0 : s;
            vreg[it] = *(const s8v*)(qkv + (rowbase + s) * TD + 2 * D + h * 64 + d0);
        }
    }
    __syncthreads();   // K in LDS (V regs also arrived)

    // ---- QK^T: band of 9 key frags per m-frag; kf shared across mf via 10-frag sweep ----
    f4v sc[2][9] = {};
    int g0 = w * 2;
    __builtin_amdgcn_s_setprio(1);
#pragma unroll
    for (int gi = 0; gi < 10; gi++) {
#pragma unroll
        for (int ks = 0; ks < 2; ks++) {
            int row = (g0 + gi) * 16 + ll;
            s8v kf = *(const s8v*)(smem + (size_t)row * 128 +
                                   (((unsigned)(ks * 64 + hl * 16)) ^ ((ll & 7) << 4)));
            if (gi < 9) sc[0][gi] = MFMA_BF16(qf[0][ks], kf, sc[0][gi]);
            if (gi > 0) sc[1][gi - 1] = MFMA_BF16(qf[1][ks], kf, sc[1][gi - 1]);
        }
    }
    __builtin_amdgcn_s_setprio(0);

    // ---- mask + scale + softmax (rows across 16 lanes of quarter-wave) ----
    float linv[2][4];
#pragma unroll
    for (int mf = 0; mf < 2; mf++) {
#pragma unroll
        for (int r = 0; r < 4; r++) {
            int ip = hl * 4 + r;                  // query pos within m-frag
            float mx = -1e30f;
#pragma unroll
            for (int nf = 0; nf < 9; nf++) {
                bool ok = (nf > 0 || ll > ip) && (nf < 8 || ll <= ip) &&
                          (blk > 0 || (g0 + mf + nf) >= 8);
                float sval = ok ? sc[mf][nf][r] * 0.125f : -1e30f;
                sc[mf][nf][r] = sval;
                mx = fmaxf(mx, sval);
            }
#pragma unroll
            for (int off = 1; off < 16; off <<= 1) mx = fmaxf(mx, __shfl_xor(mx, off, 64));
            float sum = 0.f;
#pragma unroll
            for (int nf = 0; nf < 9; nf++) {
                float p = __expf(sc[mf][nf][r] - mx);
                sc[mf][nf][r] = p;
                sum += p;
            }
#pragma unroll
            for (int off = 1; off < 16; off <<= 1) sum += __shfl_xor(sum, off, 64);
            linv[mf][r] = 1.f / sum;
        }
    }

    __syncthreads();   // all waves done reading K

    // ---- write V transposed: in-register 8x8 transpose, 8 x ds_write_b128 ----
    // Vt[d][k'] with k' = k ^ (((d>>3)&7)<<3); read side applies the same XOR.
    {
        int k0 = w * 64 + (lane >> 3) * 8;
        int d0 = (lane & 7) * 8;
#pragma unroll
        for (int e = 0; e < 8; e++) {
            int d = d0 + e;
            s8v tmp;
#pragma unroll
            for (int i = 0; i < 8; i++) tmp[i] = vreg[i][e];
            *(s8v*)(KV + d * 264 + (k0 ^ (((d >> 3) & 7) << 3))) = tmp;
        }
    }
    __syncthreads();   // Vt visible

    // ---- PV: 5 chunks of 32 keys starting at wave base w*32 ----
    f4v o[2][4] = {};
#pragma unroll
    for (int c = 0; c < 5; c++) {
#pragma unroll
        for (int mf = 0; mf < 2; mf++) {
#pragma unroll
            for (int j16 = 0; j16 < 2; j16++) {
                int nf = c * 2 + j16 - mf;
                int nfc = nf < 0 ? 0 : (nf > 8 ? 8 : nf);
#pragma unroll
                for (int r = 0; r < 4; r++) {
                    float val = (nf >= 0 && nf < 9) ? sc[mf][nfc][r] : 0.f;
                    Ps[(mf * 16 + hl * 4 + r) * PS + j16 * 16 + ll] = f2bf(val);
                }
            }
        }
        asm volatile("s_waitcnt lgkmcnt(0)" ::: "memory");
        s8v pa[2];
        pa[0] = *(const s8v*)(Ps + ll * PS + hl * 8);
        pa[1] = *(const s8v*)(Ps + (16 + ll) * PS + hl * 8);
        int cb = (w + c) * 32;
        __builtin_amdgcn_s_setprio(1);
#pragma unroll
        for (int nd = 0; nd < 4; nd++) {
            int d = nd * 16 + ll;
            int kk = (cb + hl * 8) ^ (((d >> 3) & 7) << 3);
            s8v vb = *(const s8v*)(KV + d * 264 + kk);
            o[0][nd] = MFMA_BF16(pa[0], vb, o[0][nd]);
            o[1][nd] = MFMA_BF16(pa[1], vb, o[1][nd]);
        }
        __builtin_amdgcn_s_setprio(0);
    }

    // ---- write O (bf16) ----
    unsigned short* ob = obuf + (rowbase + blk * W + w * 32) * D + h * 64;
#pragma unroll
    for (int mf = 0; mf < 2; mf++)
#pragma unroll
        for (int r = 0; r < 4; r++) {
            int row = mf * 16 + hl * 4 + r;
#pragma unroll
            for (int nd = 0; nd < 4; nd++)
                ob[(size_t)row * D + nd * 16 + ll] = f2bf(o[mf][nd][r] * linv[mf][r]);
        }
}

// ---------------- launch ----------------
extern "C" void kernel_launch(void* const* d_in, const int* in_sizes, int n_in,
                              void* d_out, int out_size, void* d_ws, size_t ws_size,
                              hipStream_t stream) {
    const float* x = (const float*)d_in[0];
    const float* g = (const float*)d_in[1];
    const float* Wqkv = (const float*)d_in[2];
    const float* Wo = (const float*)d_in[3];
    float* out = (float*)d_out;

    const int S = 4096, D = 1024, B = 4;
    const int M = B * S;  // 16384
    const int N3 = 3 * D; // 3072

    // workspace layout (bytes):
    //   [0, 6291456)            WqkvT bf16 [3072][1024]
    //   [6291456, 8388608)      WoT   bf16 [1024][1024]
    //   [8388608, 41943040)     xn    bf16 [16384][1024]  (reused as attention output)
    //   [41943040, 142606336)   qkv   bf16 [16384][3072]
    char* ws = (char*)d_ws;
    unsigned short* WqkvT = (unsigned short*)ws;
    unsigned short* WoT = (unsigned short*)(ws + 6291456);
    unsigned short* xn = (unsigned short*)(ws + 8388608);
    unsigned short* qkv = (unsigned short*)(ws + 41943040);

    transpose_cast_kernel<<<dim3((D / 32) * (N3 / 32)), dim3(256), 0, stream>>>(Wqkv, WqkvT, D, N3);
    transpose_cast_kernel<<<dim3((D / 32) * (D / 32)), dim3(256), 0, stream>>>(Wo, WoT, D, D);
    rmsnorm_kernel<<<dim3(M), dim3(256), 0, stream>>>(x, g, xn);
    gemm256_kernel<0><<<dim3((M / 256) * (N3 / 256)), dim3(512), 0, stream>>>(
        xn, WqkvT, qkv, nullptr, nullptr, M, N3, D);
    attn_kernel<<<dim3(B * 16 * (S / 128)), dim3(256), 0, stream>>>(qkv, xn);
    gemm256_kernel<1><<<dim3((M / 256) * (D / 256)), dim3(512), 0, stream>>>(
        xn, WoT, nullptr, out, x, M, D, D);
}